// Round 2
// baseline (43.679 us; speedup 1.0000x reference)
//
#include <hip/hip_runtime.h>

#define ORD 16
#define LCH 64            // chunk length
#define PCH 16384         // chunks; PCH*LCH = 2^20
#define QT  28            // truncated chunk-scan depth (0.6561^28 ~ 7e-6)
#define CPB 16            // chunks per block in k_fix

// ws float layout:
// [0, PCH*ORD)                   d_soa : d_soa[i*PCH + c] = chunk c local end state comp i
// [PCH*ORD, +ORD*LCH)            Vt    : Vt[j*LCH+k] = (a . M^k)[j]
// [.., +QT*256)                  Gmt   : Gmt[m*256 + i*16 + j] = (G^m)[j][i], G = M^LCH

__global__ __launch_bounds__(256) void k_tables(const float* __restrict__ A_w,
                                                float* __restrict__ ws) {
    __shared__ float Ma[ORD][ORD];
    __shared__ float sP[QT][ORD][ORD];
    const int tid = threadIdx.x;
    const int i = tid >> 4, j = tid & 15;
    float* Vt  = ws + PCH * ORD;
    float* Gmt = Vt + ORD * LCH;
    const float aj = A_w[j];

    // companion matrix: row 0 = a, subdiagonal identity
    Ma[i][j] = (i == 0) ? aj : ((j == i - 1) ? 1.f : 0.f);
    __syncthreads();
    // 6 squarings -> G = M^64
    for (int s = 0; s < 6; ++s) {
        float acc = 0.f;
        #pragma unroll
        for (int k = 0; k < ORD; ++k) acc += Ma[i][k] * Ma[k][j];
        __syncthreads();
        Ma[i][j] = acc;
        __syncthreads();
    }
    sP[0][i][j] = (i == j) ? 1.f : 0.f;
    sP[1][i][j] = Ma[i][j];
    __syncthreads();
    // log-doubling: given sP[1..have], compute sP[have+1..have+nn] = sP[have]*sP[m]
    int have = 1;
    while (have < QT - 1) {
        const int nn = (have < (QT - 1 - have)) ? have : (QT - 1 - have);
        for (int idx = tid; idx < nn * 256; idx += 256) {
            const int m = (idx >> 8) + 1, ii = (idx >> 4) & 15, jj = idx & 15;
            float acc = 0.f;
            #pragma unroll
            for (int l = 0; l < ORD; ++l) acc += sP[have][ii][l] * sP[m][l][jj];
            sP[have + m][ii][jj] = acc;   // writes disjoint from reads
        }
        __syncthreads();
        have += nn;
    }
    // Gmt[m][i][j] = (G^m)[j][i]
    for (int idx = tid; idx < QT * 256; idx += 256) {
        const int m = idx >> 8, ii = (idx >> 4) & 15, jj = idx & 15;
        Gmt[idx] = sP[m][jj][ii];
    }
    // V table: v_0 = a, v_{k+1}[j] = v[0]*a[j] + v[j+1]  (16-lane recurrence)
    if (tid < ORD) {
        float v = aj;  // aj == A_w[tid] here
        for (int k = 0; k < LCH; ++k) {
            Vt[tid * LCH + k] = v;
            float v0 = __shfl(v, 0, 16);
            float vn = __shfl_down(v, 1, 16);
            v = v0 * aj + ((tid < ORD - 1) ? vn : 0.f);
        }
    }
}

__global__ __launch_bounds__(64) void k_local(const float* __restrict__ u,
                                              const float* __restrict__ A_w,
                                              const float* __restrict__ B_w,
                                              float* __restrict__ out,
                                              float* __restrict__ ws) {
    __shared__ float u_s[64][81];   // [chunk-in-block][0..79], pad 81 (conflict-free)
    __shared__ float y_s[64][68];   // pad 68 -> 16B-aligned rows, float4 reads
    const int lane = threadIdx.x;        // 0..63
    const int cb = blockIdx.x * 64;      // first chunk of this block
    const int c = cb + lane;
    float* d_soa = ws;

    // stage u[cb*64 .. cb*64+4111] coalesced (float4), scatter into padded LDS
    const float* ug = u + (size_t)cb * LCH;
    for (int g4 = lane; g4 < (64 * LCH + ORD) / 4; g4 += 64) {
        const float4 v = ((const float4*)ug)[g4];
        const int g = g4 * 4;
        #pragma unroll
        for (int e = 0; e < 4; ++e) {
            const int idx = g + e, row = idx >> 6, col = idx & 63;
            const float f = (e == 0) ? v.x : (e == 1) ? v.y : (e == 2) ? v.z : v.w;
            if (row < 64) u_s[row][col] = f;
            if (col < ORD && row >= 1 && row <= 64) u_s[row - 1][64 + col] = f;
        }
    }
    float a[ORD], b[ORD];
    #pragma unroll
    for (int i = 0; i < ORD; ++i) { a[i] = A_w[i]; b[i] = B_w[i]; }
    __syncthreads();

    float uw[ORD];
    #pragma unroll
    for (int j = 0; j < ORD; ++j) uw[j] = u_s[lane][j];
    float yr[ORD];
    #pragma unroll
    for (int i = 0; i < ORD; ++i) yr[i] = 0.f;

    for (int k0 = 0; k0 < LCH; k0 += ORD) {
        #pragma unroll
        for (int kk = 0; kk < ORD; ++kk) {
            const int t = k0 + kk;
            // x[t] = sum_s b[15-s] * u[t+s]
            float x = 0.f;
            #pragma unroll
            for (int s = 0; s < ORD; ++s) x += b[15 - s] * uw[(kk + s) & 15];
            // y[t] = x + sum_i a[i]*y[t-1-i]; add a[0]*y[t-1] LAST -> 1-FMA chain
            float y = x;
            #pragma unroll
            for (int i = ORD - 1; i >= 1; --i) y += a[i] * yr[(kk - 1 - i) & 15];
            y += a[0] * yr[(kk - 1) & 15];
            yr[kk] = y;
            y_s[lane][t] = y;
            uw[kk] = u_s[lane][t + ORD];   // slide window
        }
    }
    // end state (SoA, coalesced): d[c][i] = y_loc[L-1-i] = yr[15-i]
    #pragma unroll
    for (int i = 0; i < ORD; ++i) d_soa[i * PCH + c] = yr[15 - i];
    __syncthreads();
    // coalesced float4 write of the block's 4096 local y values
    float4* out4 = (float4*)(out + (size_t)cb * LCH);
    #pragma unroll
    for (int r4 = 0; r4 < 16; ++r4) {
        const int row = r4 * 4 + (lane >> 4), col = (lane & 15) * 4;
        out4[r4 * 64 + lane] = *(const float4*)&y_s[row][col];
    }
}

__global__ __launch_bounds__(256) void k_fix(float* __restrict__ out,
                                             const float* __restrict__ ws) {
    __shared__ float sG[QT * 256];                 // 28 KB
    __shared__ float sV[ORD * LCH];                // 4 KB
    __shared__ float sd[(CPB + QT - 1) * ORD];
    __shared__ float sS[CPB][ORD];
    const float* d   = ws;
    const float* Vt  = ws + PCH * ORD;
    const float* Gmt = Vt + ORD * LCH;
    const int tid = threadIdx.x;
    const int cb = blockIdx.x * CPB;

    for (int idx = tid; idx < (QT * 256) / 4; idx += 256)
        ((float4*)sG)[idx] = ((const float4*)Gmt)[idx];
    ((float4*)sV)[tid] = ((const float4*)Vt)[tid];   // 1024 floats
    for (int idx = tid; idx < (CPB + QT - 1) * ORD; idx += 256) {
        const int cpr = cb - QT + (idx >> 4);
        sd[idx] = (cpr >= 0) ? d[(idx & 15) * PCH + cpr] : 0.f;
    }
    __syncthreads();
    // phase A: S_c[j] = sum_m (G^m)[j][.] . d[c-1-m]   (256 = CPB*ORD threads)
    {
        const int cc = tid >> 4, j = tid & 15;
        float s = 0.f;
        #pragma unroll
        for (int m = 0; m < QT; ++m) {
            const int off = (cc - 1 - m + QT) * ORD;
            #pragma unroll
            for (int i = 0; i < ORD; ++i) s += sG[m * 256 + i * 16 + j] * sd[off + i];
        }
        sS[cc][j] = s;
    }
    __syncthreads();
    // phase B: y[cL+k] += V_k . S_c   (float4 RMW, 1024 floats per block)
    {
        float4* out4 = (float4*)(out + (size_t)cb * LCH);
        const int cc = tid >> 4, k = (tid & 15) * 4;
        float4 y = out4[tid];
        #pragma unroll
        for (int j = 0; j < ORD; ++j) {
            const float s = sS[cc][j];
            y.x += sV[j * LCH + k] * s;
            y.y += sV[j * LCH + k + 1] * s;
            y.z += sV[j * LCH + k + 2] * s;
            y.w += sV[j * LCH + k + 3] * s;
        }
        out4[tid] = y;
    }
}

extern "C" void kernel_launch(void* const* d_in, const int* in_sizes, int n_in,
                              void* d_out, int out_size, void* d_ws, size_t ws_size,
                              hipStream_t stream) {
    const float* u = (const float*)d_in[0];
    const float* A = (const float*)d_in[1];
    const float* B = (const float*)d_in[2];
    float* out = (float*)d_out;
    float* ws  = (float*)d_ws;
    k_tables<<<1, 256, 0, stream>>>(A, ws);
    k_local<<<PCH / 64, 64, 0, stream>>>(u, A, B, out, ws);
    k_fix<<<PCH / CPB, 256, 0, stream>>>(out, ws);
}